// Round 12
// baseline (230.498 us; speedup 1.0000x reference)
//
#include <hip/hip_runtime.h>
#include <hip/hip_bf16.h>
#include <stdint.h>

#define BROWS 4096
#define DDIM  1024

typedef __bf16 bf16_t;
typedef __bf16 bf16x8 __attribute__((ext_vector_type(8)));
typedef float  f32x4  __attribute__((ext_vector_type(4)));

#define LDS_STRIDE 68   // bf16 elems: 64 + 4 pad -> measured conflict-free (R4/R9/R10/R11: 0)
#define GEMM_BLOCKS 512

// Lb bit layout (ballot-native): word w = (j>>8)*4 + (j&3), bit b = (j&255)>>2.

__device__ __forceinline__ unsigned short f2bf_bits(float f) {
    union { float f; unsigned int u; } v; v.f = f;
    unsigned int u = v.u;
    unsigned int r = (u + 0x7fffu + ((u >> 16) & 1u)) >> 16;
    return (unsigned short)r;
}

// ---------------------------------------------------------------------------
// Kernel 1: prep — log(q)->bf16, p->bf16, e[row], kl_div[row], zero CS/CL/EL,
//   ballot-native label bitmask. Block 0 also zeroes the gemm completion
//   counter (ws is poisoned 0xAA before every launch).
// ---------------------------------------------------------------------------
__global__ __launch_bounds__(256) void prep_kernel(
    const float* __restrict__ q, const float* __restrict__ p,
    const float* __restrict__ L,
    bf16_t* __restrict__ lqb, bf16_t* __restrict__ pb,
    uint64_t* __restrict__ Lb,
    float* __restrict__ e, float* __restrict__ kld,
    float* __restrict__ CS, float* __restrict__ CL, float* __restrict__ EL,
    int* __restrict__ done)
{
    const int row = blockIdx.x;
    const int t   = threadIdx.x;
    const int wv  = t >> 6, ln = t & 63;

    const float4* q4 = (const float4*)(q + (size_t)row * DDIM);
    const float4* p4 = (const float4*)(p + (size_t)row * DDIM);
    float4 qv = q4[t];
    float4 pv = p4[t];

    float lq0 = __logf(qv.x), lq1 = __logf(qv.y), lq2 = __logf(qv.z), lq3 = __logf(qv.w);
    float lp0 = __logf(pv.x), lp1 = __logf(pv.y), lp2 = __logf(pv.z), lp3 = __logf(pv.w);

    float esum = pv.x * lp0 + pv.y * lp1 + pv.z * lp2 + pv.w * lp3;
    float ksum = pv.x * (lp0 - lq0) + pv.y * (lp1 - lq1)
               + pv.z * (lp2 - lq2) + pv.w * (lp3 - lq3);

    ushort4 uq, up;
    uq.x = f2bf_bits(lq0); uq.y = f2bf_bits(lq1); uq.z = f2bf_bits(lq2); uq.w = f2bf_bits(lq3);
    up.x = f2bf_bits(pv.x); up.y = f2bf_bits(pv.y); up.z = f2bf_bits(pv.z); up.w = f2bf_bits(pv.w);
    ((ushort4*)(lqb + (size_t)row * DDIM))[t] = uq;
    ((ushort4*)(pb  + (size_t)row * DDIM))[t] = up;

    const float4* L4 = (const float4*)(L + (size_t)row * BROWS);
    #pragma unroll
    for (int s = 0; s < 4; s++) {
        float4 lv = L4[s * 256 + t];
        unsigned long long b0 = __ballot(lv.x != 0.0f);
        unsigned long long b1 = __ballot(lv.y != 0.0f);
        unsigned long long b2 = __ballot(lv.z != 0.0f);
        unsigned long long b3 = __ballot(lv.w != 0.0f);
        if (ln < 4) {
            unsigned long long w = (ln == 0) ? b0 : (ln == 1) ? b1 : (ln == 2) ? b2 : b3;
            Lb[(size_t)row * 64 + (s * 4 + wv) * 4 + ln] = w;
        }
    }

    if (t == 0) { CS[row] = 0.f; CL[row] = 0.f; EL[row] = 0.f; }
    if (row == 0 && t == 0) *done = 0;

    #pragma unroll
    for (int off = 32; off > 0; off >>= 1) {
        esum += __shfl_down(esum, off);
        ksum += __shfl_down(ksum, off);
    }
    __shared__ float se[4], sk[4];
    if (ln == 0) { se[wv] = esum; sk[wv] = ksum; }
    __syncthreads();
    if (t == 0) {
        e[row]   = se[0] + se[1] + se[2] + se[3];
        kld[row] = (sk[0] + sk[1] + sk[2] + sk[3]) * (1.0f / DDIM);
    }
}

// ---------------------------------------------------------------------------
// Kernel 2: cross = log_q @ p^T — R10/R11 verbatim K-loop + XCD swizzle
//   (measured 54-58 us, WRITE 15 MB, 0 conflicts, FETCH 27.5 MB) + FUSED
//   FINAL: last block to finish (device-scope counter) reduces pos/neg.
// ---------------------------------------------------------------------------
__global__ __launch_bounds__(512, 4) void gemm_epi_kernel(
    const bf16_t* __restrict__ Abf,   // log_q [B,D]
    const bf16_t* __restrict__ Bbf,   // p     [B,D]
    const uint64_t* __restrict__ Lb,  // [B,64] ballot-native bitmask
    const float*  __restrict__ e,     // [B]
    const float*  __restrict__ kld,   // [B]
    float* __restrict__ CS, float* __restrict__ CL, float* __restrict__ EL,
    int* __restrict__ done, float* __restrict__ out)
{
    __shared__ __align__(16) bf16_t As[256 * LDS_STRIDE];  // 34 KB
    __shared__ __align__(16) bf16_t Bs[128 * LDS_STRIDE];  // 17 KB

    const int t    = threadIdx.x;
    // XCD swizzle: b -> (i_idx 0..15, j_idx 0..31), patch-of-8x8 per XCD
    const int b     = blockIdx.x;
    const int xcd   = b & 7;
    const int s     = b >> 3;                      // 0..63 within patch
    const int i_idx = (xcd >> 2) * 8 + (s >> 3);   // 0..15
    const int j_idx = (xcd & 3) * 8 + (s & 7);     // 0..31
    const int i0   = i_idx * 256;
    const int j0   = j_idx * 128;
    const int wave = t >> 6;
    const int lane = t & 63;
    const int q4   = lane >> 4;
    const int ln   = lane & 15;
    const int wrow = wave & 3;    // 4 i-subtiles
    const int wcol = wave >> 2;   // 2 j-subtiles

    f32x4 acc[4][4];
    #pragma unroll
    for (int a = 0; a < 4; a++)
        #pragma unroll
        for (int bq = 0; bq < 4; bq++)
            acc[a][bq] = (f32x4){0.f, 0.f, 0.f, 0.f};

    const bf16_t* gAp[4]; int lA[4];
    const bf16_t* gBp[2]; int lB[2];
    #pragma unroll
    for (int n = 0; n < 4; n++) {
        const int id = t + n * 512;
        gAp[n] = Abf + (size_t)(i0 + (id >> 3)) * DDIM + (id & 7) * 8;
        lA[n]  = (id >> 3) * LDS_STRIDE + (id & 7) * 8;
    }
    #pragma unroll
    for (int n = 0; n < 2; n++) {
        const int id = t + n * 512;
        gBp[n] = Bbf + (size_t)(j0 + (id >> 3)) * DDIM + (id & 7) * 8;
        lB[n]  = (id >> 3) * LDS_STRIDE + (id & 7) * 8;
    }

    bf16x8 pfA[4], pfB[2];
    #pragma unroll
    for (int n = 0; n < 4; n++) pfA[n] = *(const bf16x8*)(gAp[n]);
    #pragma unroll
    for (int n = 0; n < 2; n++) pfB[n] = *(const bf16x8*)(gBp[n]);

    #pragma unroll 1
    for (int c = 0; c < DDIM / 64; ++c) {
        __syncthreads();
        #pragma unroll
        for (int n = 0; n < 4; n++) *(bf16x8*)(As + lA[n]) = pfA[n];
        #pragma unroll
        for (int n = 0; n < 2; n++) *(bf16x8*)(Bs + lB[n]) = pfB[n];
        __syncthreads();

        if (c + 1 < DDIM / 64) {
            const int k = (c + 1) * 64;
            #pragma unroll
            for (int n = 0; n < 4; n++) pfA[n] = *(const bf16x8*)(gAp[n] + k);
            #pragma unroll
            for (int n = 0; n < 2; n++) pfB[n] = *(const bf16x8*)(gBp[n] + k);
        }

        #pragma unroll
        for (int ks = 0; ks < 2; ks++) {
            bf16x8 af[4], bfr[4];
            #pragma unroll
            for (int mi = 0; mi < 4; mi++)
                af[mi] = *(const bf16x8*)(As + (wrow * 64 + mi * 16 + ln) * LDS_STRIDE
                                             + ks * 32 + q4 * 8);
            #pragma unroll
            for (int ni = 0; ni < 4; ni++)
                bfr[ni] = *(const bf16x8*)(Bs + (wcol * 64 + ni * 16 + ln) * LDS_STRIDE
                                              + ks * 32 + q4 * 8);
            #pragma unroll
            for (int mi = 0; mi < 4; mi++)
                #pragma unroll
                for (int ni = 0; ni < 4; ni++)
                    acc[mi][ni] = __builtin_amdgcn_mfma_f32_16x16x32_bf16(
                        af[mi], bfr[ni], acc[mi][ni], 0, 0, 0);
        }
    }

    // ---- epilogue: C/D col = lane&15 (=j), row = quad*4+reg (=i) ----
    const int i_base = i0 + wrow * 64;
    const int j_base = j0 + wcol * 64;
    const int wbase  = (j_base >> 8) * 4 + (ln & 3);
    const int bshift = ((j_base & 255) >> 2) + (ln >> 2);

    float e_j[4];
    #pragma unroll
    for (int ni = 0; ni < 4; ni++) e_j[ni] = e[j_base + ni * 16 + ln];

    #pragma unroll
    for (int mi = 0; mi < 4; mi++) {
        #pragma unroll
        for (int r = 0; r < 4; r++) {
            const int i = i_base + mi * 16 + q4 * 4 + r;
            const uint64_t m  = Lb[(size_t)i * 64 + wbase];
            const uint64_t ms = m >> bshift;
            float cs = 0.f, cl = 0.f, el = 0.f;
            #pragma unroll
            for (int ni = 0; ni < 4; ni++) {
                float c = acc[mi][ni][r];
                cs += c;
                if ((ms >> (ni * 4)) & 1ull) { cl += c; el += e_j[ni]; }
            }
            #pragma unroll
            for (int sft = 1; sft < 16; sft <<= 1) {
                cs += __shfl_xor(cs, sft);
                cl += __shfl_xor(cl, sft);
                el += __shfl_xor(el, sft);
            }
            if (ln == 0) {
                atomicAdd(&CS[i], cs);
                atomicAdd(&CL[i], cl);
                atomicAdd(&EL[i], el);
            }
        }
    }

    // ---- fused final: last block to finish reduces sum_i pos/neg ----
    __threadfence();                       // release: my atomics visible device-wide
    __shared__ int sIsLast;
    if (t == 0) {
        int old = atomicAdd(done, 1);
        sIsLast = (old == GEMM_BLOCKS - 1) ? 1 : 0;
    }
    __syncthreads();
    if (sIsLast) {
        __threadfence();                   // acquire: all blocks' atomics visible
        __shared__ float sred[8];
        __shared__ float sEtot;
        const int wv8 = t >> 6;

        float ssum = 0.f;
        #pragma unroll
        for (int j = t; j < BROWS; j += 512) ssum += e[j];
        #pragma unroll
        for (int off = 32; off > 0; off >>= 1) ssum += __shfl_down(ssum, off);
        if (lane == 0) sred[wv8] = ssum;
        __syncthreads();
        if (t == 0) {
            float a = 0.f;
            #pragma unroll
            for (int k = 0; k < 8; k++) a += sred[k];
            sEtot = a;
        }
        __syncthreads();
        const float Etot = sEtot;
        const float invD = 1.0f / DDIM;

        float rs = 0.f;
        #pragma unroll
        for (int i = t; i < BROWS; i += 512) {
            float el = __hip_atomic_load(&EL[i], __ATOMIC_RELAXED, __HIP_MEMORY_SCOPE_AGENT);
            float cl = __hip_atomic_load(&CL[i], __ATOMIC_RELAXED, __HIP_MEMORY_SCOPE_AGENT);
            float cs = __hip_atomic_load(&CS[i], __ATOMIC_RELAXED, __HIP_MEMORY_SCOPE_AGENT);
            float pos = kld[i] + (el - cl) * invD;
            float neg = (Etot - el - cs + cl) * invD;
            rs += pos / neg;
        }
        __syncthreads();
        #pragma unroll
        for (int off = 32; off > 0; off >>= 1) rs += __shfl_down(rs, off);
        if (lane == 0) sred[wv8] = rs;
        __syncthreads();
        if (t == 0) {
            float a = 0.f;
            #pragma unroll
            for (int k = 0; k < 8; k++) a += sred[k];
            out[0] = a;
        }
    }
}

// ---------------------------------------------------------------------------
extern "C" void kernel_launch(void* const* d_in, const int* in_sizes, int n_in,
                              void* d_out, int out_size, void* d_ws, size_t ws_size,
                              hipStream_t stream)
{
    const float* q = (const float*)d_in[0];
    const float* p = (const float*)d_in[1];
    const float* L = (const float*)d_in[2];
    float* out = (float*)d_out;

    char* ws = (char*)d_ws;
    bf16_t* lqb = (bf16_t*)ws;                                    // 8 MB
    bf16_t* pb  = (bf16_t*)(ws + (size_t)BROWS * DDIM * 2);       // 8 MB
    float*  e   = (float*)(ws + (size_t)BROWS * DDIM * 4);        // 16 KB
    float*  kld = e + BROWS;
    float*  CS  = kld + BROWS;
    float*  CL  = CS + BROWS;
    float*  EL  = CL + BROWS;
    uint64_t* Lb = (uint64_t*)(EL + BROWS);                       // 2 MB
    int*    done = (int*)(Lb + (size_t)BROWS * 64);

    prep_kernel<<<BROWS, 256, 0, stream>>>(q, p, L, lqb, pb, Lb, e, kld, CS, CL, EL, done);

    gemm_epi_kernel<<<GEMM_BLOCKS, 512, 0, stream>>>(lqb, pb, Lb, e, kld,
                                                     CS, CL, EL, done, out);
}

// Round 13
// 174.644 us; speedup vs baseline: 1.3198x; 1.3198x over previous
//
#include <hip/hip_runtime.h>
#include <hip/hip_bf16.h>
#include <stdint.h>

#define BROWS 4096
#define DDIM  1024

typedef __bf16 bf16_t;
typedef __bf16 bf16x8 __attribute__((ext_vector_type(8)));
typedef float  f32x4  __attribute__((ext_vector_type(4)));

#define LDS_STRIDE 68   // bf16 elems: 64 + 4 pad -> measured conflict-free
#define GEMM_BLOCKS 512

// Lb bit layout (ballot-native): word w = (j>>8)*4 + (j&3), bit b = (j&255)>>2.

__device__ __forceinline__ unsigned short f2bf_bits(float f) {
    union { float f; unsigned int u; } v; v.f = f;
    unsigned int u = v.u;
    unsigned int r = (u + 0x7fffu + ((u >> 16) & 1u)) >> 16;
    return (unsigned short)r;
}

// ---------------------------------------------------------------------------
// Kernel 1: prep — log(q)->bf16, p->bf16, e[row], kl_div[row], zero CS/CL/EL,
//   ballot-native label bitmask; block 0 zeroes the completion counter.
// ---------------------------------------------------------------------------
__global__ __launch_bounds__(256) void prep_kernel(
    const float* __restrict__ q, const float* __restrict__ p,
    const float* __restrict__ L,
    bf16_t* __restrict__ lqb, bf16_t* __restrict__ pb,
    uint64_t* __restrict__ Lb,
    float* __restrict__ e, float* __restrict__ kld,
    float* __restrict__ CS, float* __restrict__ CL, float* __restrict__ EL,
    int* __restrict__ done)
{
    const int row = blockIdx.x;
    const int t   = threadIdx.x;
    const int wv  = t >> 6, ln = t & 63;

    const float4* q4 = (const float4*)(q + (size_t)row * DDIM);
    const float4* p4 = (const float4*)(p + (size_t)row * DDIM);
    float4 qv = q4[t];
    float4 pv = p4[t];

    float lq0 = __logf(qv.x), lq1 = __logf(qv.y), lq2 = __logf(qv.z), lq3 = __logf(qv.w);
    float lp0 = __logf(pv.x), lp1 = __logf(pv.y), lp2 = __logf(pv.z), lp3 = __logf(pv.w);

    float esum = pv.x * lp0 + pv.y * lp1 + pv.z * lp2 + pv.w * lp3;
    float ksum = pv.x * (lp0 - lq0) + pv.y * (lp1 - lq1)
               + pv.z * (lp2 - lq2) + pv.w * (lp3 - lq3);

    ushort4 uq, up;
    uq.x = f2bf_bits(lq0); uq.y = f2bf_bits(lq1); uq.z = f2bf_bits(lq2); uq.w = f2bf_bits(lq3);
    up.x = f2bf_bits(pv.x); up.y = f2bf_bits(pv.y); up.z = f2bf_bits(pv.z); up.w = f2bf_bits(pv.w);
    ((ushort4*)(lqb + (size_t)row * DDIM))[t] = uq;
    ((ushort4*)(pb  + (size_t)row * DDIM))[t] = up;

    const float4* L4 = (const float4*)(L + (size_t)row * BROWS);
    #pragma unroll
    for (int s = 0; s < 4; s++) {
        float4 lv = L4[s * 256 + t];
        unsigned long long b0 = __ballot(lv.x != 0.0f);
        unsigned long long b1 = __ballot(lv.y != 0.0f);
        unsigned long long b2 = __ballot(lv.z != 0.0f);
        unsigned long long b3 = __ballot(lv.w != 0.0f);
        if (ln < 4) {
            unsigned long long w = (ln == 0) ? b0 : (ln == 1) ? b1 : (ln == 2) ? b2 : b3;
            Lb[(size_t)row * 64 + (s * 4 + wv) * 4 + ln] = w;
        }
    }

    if (t == 0) { CS[row] = 0.f; CL[row] = 0.f; EL[row] = 0.f; }
    if (row == 0 && t == 0) *done = 0;

    #pragma unroll
    for (int off = 32; off > 0; off >>= 1) {
        esum += __shfl_down(esum, off);
        ksum += __shfl_down(ksum, off);
    }
    __shared__ float se[4], sk[4];
    if (ln == 0) { se[wv] = esum; sk[wv] = ksum; }
    __syncthreads();
    if (t == 0) {
        e[row]   = se[0] + se[1] + se[2] + se[3];
        kld[row] = (sk[0] + sk[1] + sk[2] + sk[3]) * (1.0f / DDIM);
    }
}

// ---------------------------------------------------------------------------
// Kernel 2: cross = log_q @ p^T — R10/R11 verbatim K-loop + XCD swizzle,
//   FUSED FINAL v2: no __threadfence (R12's +58 us was L2 writeback per
//   block). Ordering: CS/CL/EL and `done` are touched ONLY by device-scope
//   atomics (coherent point, G12/m20); each block's adds complete before its
//   done-increment via the explicit vmcnt(0)+barrier drain.
// ---------------------------------------------------------------------------
__global__ __launch_bounds__(512, 4) void gemm_epi_kernel(
    const bf16_t* __restrict__ Abf,   // log_q [B,D]
    const bf16_t* __restrict__ Bbf,   // p     [B,D]
    const uint64_t* __restrict__ Lb,  // [B,64] ballot-native bitmask
    const float*  __restrict__ e,     // [B]
    const float*  __restrict__ kld,   // [B]
    float* __restrict__ CS, float* __restrict__ CL, float* __restrict__ EL,
    int* __restrict__ done, float* __restrict__ out)
{
    __shared__ __align__(16) bf16_t As[256 * LDS_STRIDE];  // 34 KB
    __shared__ __align__(16) bf16_t Bs[128 * LDS_STRIDE];  // 17 KB

    const int t    = threadIdx.x;
    const int b     = blockIdx.x;
    const int xcd   = b & 7;
    const int s     = b >> 3;
    const int i_idx = (xcd >> 2) * 8 + (s >> 3);   // 0..15
    const int j_idx = (xcd & 3) * 8 + (s & 7);     // 0..31
    const int i0   = i_idx * 256;
    const int j0   = j_idx * 128;
    const int wave = t >> 6;
    const int lane = t & 63;
    const int q4   = lane >> 4;
    const int ln   = lane & 15;
    const int wrow = wave & 3;
    const int wcol = wave >> 2;

    f32x4 acc[4][4];
    #pragma unroll
    for (int a = 0; a < 4; a++)
        #pragma unroll
        for (int bq = 0; bq < 4; bq++)
            acc[a][bq] = (f32x4){0.f, 0.f, 0.f, 0.f};

    const bf16_t* gAp[4]; int lA[4];
    const bf16_t* gBp[2]; int lB[2];
    #pragma unroll
    for (int n = 0; n < 4; n++) {
        const int id = t + n * 512;
        gAp[n] = Abf + (size_t)(i0 + (id >> 3)) * DDIM + (id & 7) * 8;
        lA[n]  = (id >> 3) * LDS_STRIDE + (id & 7) * 8;
    }
    #pragma unroll
    for (int n = 0; n < 2; n++) {
        const int id = t + n * 512;
        gBp[n] = Bbf + (size_t)(j0 + (id >> 3)) * DDIM + (id & 7) * 8;
        lB[n]  = (id >> 3) * LDS_STRIDE + (id & 7) * 8;
    }

    bf16x8 pfA[4], pfB[2];
    #pragma unroll
    for (int n = 0; n < 4; n++) pfA[n] = *(const bf16x8*)(gAp[n]);
    #pragma unroll
    for (int n = 0; n < 2; n++) pfB[n] = *(const bf16x8*)(gBp[n]);

    #pragma unroll 1
    for (int c = 0; c < DDIM / 64; ++c) {
        __syncthreads();
        #pragma unroll
        for (int n = 0; n < 4; n++) *(bf16x8*)(As + lA[n]) = pfA[n];
        #pragma unroll
        for (int n = 0; n < 2; n++) *(bf16x8*)(Bs + lB[n]) = pfB[n];
        __syncthreads();

        if (c + 1 < DDIM / 64) {
            const int k = (c + 1) * 64;
            #pragma unroll
            for (int n = 0; n < 4; n++) pfA[n] = *(const bf16x8*)(gAp[n] + k);
            #pragma unroll
            for (int n = 0; n < 2; n++) pfB[n] = *(const bf16x8*)(gBp[n] + k);
        }

        #pragma unroll
        for (int ks = 0; ks < 2; ks++) {
            bf16x8 af[4], bfr[4];
            #pragma unroll
            for (int mi = 0; mi < 4; mi++)
                af[mi] = *(const bf16x8*)(As + (wrow * 64 + mi * 16 + ln) * LDS_STRIDE
                                             + ks * 32 + q4 * 8);
            #pragma unroll
            for (int ni = 0; ni < 4; ni++)
                bfr[ni] = *(const bf16x8*)(Bs + (wcol * 64 + ni * 16 + ln) * LDS_STRIDE
                                              + ks * 32 + q4 * 8);
            #pragma unroll
            for (int mi = 0; mi < 4; mi++)
                #pragma unroll
                for (int ni = 0; ni < 4; ni++)
                    acc[mi][ni] = __builtin_amdgcn_mfma_f32_16x16x32_bf16(
                        af[mi], bfr[ni], acc[mi][ni], 0, 0, 0);
        }
    }

    // ---- epilogue: C/D col = lane&15 (=j), row = quad*4+reg (=i) ----
    const int i_base = i0 + wrow * 64;
    const int j_base = j0 + wcol * 64;
    const int wbase  = (j_base >> 8) * 4 + (ln & 3);
    const int bshift = ((j_base & 255) >> 2) + (ln >> 2);

    float e_j[4];
    #pragma unroll
    for (int ni = 0; ni < 4; ni++) e_j[ni] = e[j_base + ni * 16 + ln];

    #pragma unroll
    for (int mi = 0; mi < 4; mi++) {
        #pragma unroll
        for (int r = 0; r < 4; r++) {
            const int i = i_base + mi * 16 + q4 * 4 + r;
            const uint64_t m  = Lb[(size_t)i * 64 + wbase];
            const uint64_t ms = m >> bshift;
            float cs = 0.f, cl = 0.f, el = 0.f;
            #pragma unroll
            for (int ni = 0; ni < 4; ni++) {
                float c = acc[mi][ni][r];
                cs += c;
                if ((ms >> (ni * 4)) & 1ull) { cl += c; el += e_j[ni]; }
            }
            #pragma unroll
            for (int sft = 1; sft < 16; sft <<= 1) {
                cs += __shfl_xor(cs, sft);
                cl += __shfl_xor(cl, sft);
                el += __shfl_xor(el, sft);
            }
            if (ln == 0) {
                atomicAdd(&CS[i], cs);
                atomicAdd(&CL[i], cl);
                atomicAdd(&EL[i], el);
            }
        }
    }

    // ---- fused final v2: no cache-maintenance fences ----
    // Each wave's atomics drain (vmcnt(0)) before the barrier; after the
    // barrier, all 8 waves' adds have completed at the device coherent point.
    __asm__ volatile("s_waitcnt vmcnt(0)" ::: "memory");
    __syncthreads();
    __shared__ int sIsLast;
    if (t == 0) sIsLast = (atomicAdd(done, 1) == GEMM_BLOCKS - 1) ? 1 : 0;
    __syncthreads();
    if (sIsLast) {
        __shared__ float sred[8];
        __shared__ float sEtot;
        const int wv8 = t >> 6;

        float ssum = 0.f;
        #pragma unroll
        for (int j = t; j < BROWS; j += 512) ssum += e[j];
        #pragma unroll
        for (int off = 32; off > 0; off >>= 1) ssum += __shfl_down(ssum, off);
        if (lane == 0) sred[wv8] = ssum;
        __syncthreads();
        if (t == 0) {
            float a = 0.f;
            #pragma unroll
            for (int k = 0; k < 8; k++) a += sred[k];
            sEtot = a;
        }
        __syncthreads();
        const float Etot = sEtot;
        const float invD = 1.0f / DDIM;

        float rs = 0.f;
        #pragma unroll
        for (int i = t; i < BROWS; i += 512) {
            float el = __hip_atomic_load(&EL[i], __ATOMIC_RELAXED, __HIP_MEMORY_SCOPE_AGENT);
            float cl = __hip_atomic_load(&CL[i], __ATOMIC_RELAXED, __HIP_MEMORY_SCOPE_AGENT);
            float cs = __hip_atomic_load(&CS[i], __ATOMIC_RELAXED, __HIP_MEMORY_SCOPE_AGENT);
            float pos = kld[i] + (el - cl) * invD;
            float neg = (Etot - el - cs + cl) * invD;
            rs += pos / neg;
        }
        __syncthreads();
        #pragma unroll
        for (int off = 32; off > 0; off >>= 1) rs += __shfl_down(rs, off);
        if (lane == 0) sred[wv8] = rs;
        __syncthreads();
        if (t == 0) {
            float a = 0.f;
            #pragma unroll
            for (int k = 0; k < 8; k++) a += sred[k];
            out[0] = a;
        }
    }
}

// ---------------------------------------------------------------------------
extern "C" void kernel_launch(void* const* d_in, const int* in_sizes, int n_in,
                              void* d_out, int out_size, void* d_ws, size_t ws_size,
                              hipStream_t stream)
{
    const float* q = (const float*)d_in[0];
    const float* p = (const float*)d_in[1];
    const float* L = (const float*)d_in[2];
    float* out = (float*)d_out;

    char* ws = (char*)d_ws;
    bf16_t* lqb = (bf16_t*)ws;                                    // 8 MB
    bf16_t* pb  = (bf16_t*)(ws + (size_t)BROWS * DDIM * 2);       // 8 MB
    float*  e   = (float*)(ws + (size_t)BROWS * DDIM * 4);        // 16 KB
    float*  kld = e + BROWS;
    float*  CS  = kld + BROWS;
    float*  CL  = CS + BROWS;
    float*  EL  = CL + BROWS;
    uint64_t* Lb = (uint64_t*)(EL + BROWS);                       // 2 MB
    int*    done = (int*)(Lb + (size_t)BROWS * 64);

    prep_kernel<<<BROWS, 256, 0, stream>>>(q, p, L, lqb, pb, Lb, e, kld, CS, CL, EL, done);

    gemm_epi_kernel<<<GEMM_BLOCKS, 512, 0, stream>>>(lqb, pb, Lb, e, kld,
                                                     CS, CL, EL, done, out);
}